// Round 7
// baseline (2894.445 us; speedup 1.0000x reference)
//
#include <hip/hip_runtime.h>
#include <cstdint>
#include <cstddef>

#define T_STEPS 100
#define IN_DIM  140
#define HDIM    256
#define BTOT    4096
#define MROWS   32
#define NBLK    (BTOT/MROWS)  // 128 blocks
#define NTHR    1024          // 16 waves

typedef _Float16 f16;
typedef _Float16 f16x8 __attribute__((ext_vector_type(8)));
typedef float    f32x4 __attribute__((ext_vector_type(4)));

// K dims (padded to 32): gates0 K=416 (x 160 incl pad + h0 256), gates1 K=512, adv K=256
#define NS0 13
#define NS1 16
#define NSA 8
#define NH0 (2*NS0)           // 26 half-slices
#define NH1 (2*NS1)           // 32
// fragment = 64 lanes x 8 f16 = 512 elems = 1KB
#define E0 (NS0*64*512)       // 425984
#define E1 (NS1*64*512)       // 524288
#define EA (NSA*16*512)       // 65536
#define F16TOT (E0+E1+EA)     // 1015808 f16 = ~2MB
#define EB 2048               // 2x1024 fp32 biases
#define PREP_TOT (F16TOT+EB)  // 1017856 = 3976*256

// LDS activation tile: cols 0-159 x(padded), 160-415 h0, 416-671 h1, 672-679 pad
#define ACOLS 680
#define H0COL 160
#define H1COL 416

__device__ __forceinline__ float sigmoidf_(float x) {
    return 1.0f / (1.0f + __expf(-x));
}
__device__ __forceinline__ float tanhf_(float x) {
    return 1.0f - 2.0f / (__expf(2.0f * x) + 1.0f);
}

// Pack weights into MFMA B-fragment order (fp16) + folded fp32 biases.
// Frag (ks, nt): lane l, elem e -> B[k = ks*32 + (l>>4)*8 + e][n = nt*16 + (l&15)]
__global__ void prep(const float* __restrict__ Wih0, const float* __restrict__ Whh0,
                     const float* __restrict__ bih0, const float* __restrict__ bhh0,
                     const float* __restrict__ Wih1, const float* __restrict__ Whh1,
                     const float* __restrict__ bih1, const float* __restrict__ bhh1,
                     const float* __restrict__ Wa1,  f16* __restrict__ wsf,
                     float* __restrict__ wsb)
{
    int idx = blockIdx.x * 256 + threadIdx.x;
    if (idx < E0) {
        int e = idx & 7, l = (idx >> 3) & 63, fi = idx >> 9;
        int nt = fi & 63, ks = fi >> 6;
        int k = ks * 32 + ((l >> 4) << 3) + e;
        int n = nt * 16 + (l & 15);
        float v = (k < 160) ? (k < IN_DIM ? Wih0[n * IN_DIM + k] : 0.f)
                            : Whh0[n * HDIM + (k - 160)];
        wsf[idx] = (f16)v;
    } else if (idx < E0 + E1) {
        int i2 = idx - E0;
        int e = i2 & 7, l = (i2 >> 3) & 63, fi = i2 >> 9;
        int nt = fi & 63, ks = fi >> 6;
        int k = ks * 32 + ((l >> 4) << 3) + e;
        int n = nt * 16 + (l & 15);
        float v = (k < HDIM) ? Wih1[n * HDIM + k] : Whh1[n * HDIM + (k - HDIM)];
        wsf[idx] = (f16)v;
    } else if (idx < F16TOT) {
        int i3 = idx - (E0 + E1);
        int e = i3 & 7, l = (i3 >> 3) & 63, fi = i3 >> 9;
        int nt = fi & 15, ks = fi >> 4;
        int k = ks * 32 + ((l >> 4) << 3) + e;
        int j = nt * 16 + (l & 15);
        wsf[idx] = (f16)Wa1[j * HDIM + k];
    } else if (idx < PREP_TOT) {
        int i4 = idx - F16TOT;
        if (i4 < 1024) wsb[i4] = bih0[i4] + bhh0[i4];
        else           wsb[i4] = bih1[i4 - 1024] + bhh1[i4 - 1024];
    }
}

#define GLOAD_LDS(gsrc, ldst)                                              \
    __builtin_amdgcn_global_load_lds(                                      \
        (const __attribute__((address_space(1))) void*)(gsrc),             \
        (__attribute__((address_space(3))) void*)(ldst), 16, 0, 0)

template<int N>
__device__ __forceinline__ void wait_vm() {
    asm volatile("s_waitcnt vmcnt(%0)" :: "i"(N) : "memory");
    __builtin_amdgcn_sched_barrier(0);
}
#define WAIT_LGKM0 do { asm volatile("s_waitcnt lgkmcnt(0)" ::: "memory"); \
                        __builtin_amdgcn_sched_barrier(0); } while (0)

__global__ __launch_bounds__(NTHR) void lstm_mfma(
    const float* __restrict__ x, const f16* __restrict__ wsf,
    const float* __restrict__ wsb, const float* __restrict__ Wa2,
    const float* __restrict__ ba1, const float* __restrict__ ba2,
    float* __restrict__ out)
{
    __shared__ __align__(16) f16 A[MROWS][ACOLS];       // 43520 B
    __shared__ __align__(16) f16 Bst[16][3][1024];      // 16 waves x 3 bufs x 2KB = 96KB
    __shared__ float red[16][MROWS];                    // 2KB

    const int tid = threadIdx.x;
    const int l   = tid & 63;
    const int w   = tid >> 6;         // wave 0..15 == n-frag column nt
    const int lm  = l & 15;           // A-row(within m-tile) / C-col(n) lane coord
    const int lk  = (l >> 4) << 3;    // k-offset within a 32-slice
    const int m0  = (l >> 4) << 2;    // C rows m0..m0+3 (within m-tile)
    const int row0 = blockIdx.x * MROWS;

    const f16* W0 = wsf;
    const f16* W1 = wsf + E0;
    const f16* WA = wsf + E0 + E1;
    f16* wbuf = &Bst[w][0][0];        // ring of 3 buffers, 1024 f16 (2KB) each

    // zero activation tile
    for (int i = tid; i < MROWS * ACOLS; i += NTHR) ((f16*)A)[i] = (f16)0.f;

    const int u = w * 16 + lm;        // hidden unit owned by this thread
    float b0v[4], b1v[4];
    #pragma unroll
    for (int g = 0; g < 4; g++) {
        b0v[g] = wsb[g * 256 + u];
        b1v[g] = wsb[1024 + g * 256 + u];
    }
    const float bAv  = ba1[u];
    const float wa2v = Wa2[u];
    const float ba2v = ba2[0];

    float c0s[2][4], c1s[2][4];
    #pragma unroll
    for (int mt = 0; mt < 2; mt++)
        #pragma unroll
        for (int r = 0; r < 4; r++) { c0s[mt][r] = 0.f; c1s[mt][r] = 0.f; }

    __syncthreads();

    #pragma unroll 1
    for (int t = 0; t < T_STEPS; t++) {
        // ---- stage x_t (fp32 -> fp16) ----
        for (int i = tid; i < MROWS * IN_DIM; i += NTHR) {
            int b = i / IN_DIM, k = i - b * IN_DIM;
            A[b][k] = (f16)x[(size_t)(row0 + b) * (T_STEPS * IN_DIM) + (size_t)t * IN_DIM + k];
        }
        __syncthreads();   // B1: x visible

        // ======== gates0: C[32x1024] = A[:,0:416] * W0 (13 slices, 26 halves) ========
        f32x4 acc[2][4];
        #pragma unroll
        for (int mt = 0; mt < 2; mt++)
            #pragma unroll
            for (int g = 0; g < 4; g++) {
                float b = b0v[g];
                acc[mt][g] = (f32x4){b, b, b, b};
            }
        // prologue: halves 0,1 -> buf0,buf1 (2 loads each)
        WAIT_LGKM0;
        #pragma unroll
        for (int d = 0; d < 2; d++)
            GLOAD_LDS(W0 + ((size_t)(0 * 64 + d * 16 + w)) * 512 + l * 8, wbuf + d * 512);
        #pragma unroll
        for (int d = 0; d < 2; d++)
            GLOAD_LDS(W0 + ((size_t)(0 * 64 + (2 + d) * 16 + w)) * 512 + l * 8, wbuf + 1024 + d * 512);

        f16x8 a0, a1;
        #pragma unroll 1
        for (int ks = 0; ks < NS0; ks++) {
            // ---- even half h=2ks (gates 0,1) ----
            {
                const int h = 2 * ks;
                WAIT_LGKM0;          // reads of half h-1 done -> buf[(h+2)%3] free
                if (h + 2 < NH0) {
                    const int hs = h + 2, kss = hs >> 1, gb = (hs & 1) * 2;
                    f16* db = wbuf + ((hs % 3) << 10);
                    #pragma unroll
                    for (int d = 0; d < 2; d++)
                        GLOAD_LDS(W0 + ((size_t)(kss * 64 + (gb + d) * 16 + w)) * 512 + l * 8, db + d * 512);
                    wait_vm<4>();
                } else {
                    wait_vm<2>();
                }
                a0 = *(const f16x8*)&A[lm     ][ks * 32 + lk];
                a1 = *(const f16x8*)&A[16 + lm][ks * 32 + lk];
                const f16* rb = wbuf + ((h % 3) << 10);
                f16x8 bf0 = *(const f16x8*)(rb + l * 8);
                f16x8 bf1 = *(const f16x8*)(rb + 512 + l * 8);
                acc[0][0] = __builtin_amdgcn_mfma_f32_16x16x32_f16(a0, bf0, acc[0][0], 0, 0, 0);
                acc[1][0] = __builtin_amdgcn_mfma_f32_16x16x32_f16(a1, bf0, acc[1][0], 0, 0, 0);
                acc[0][1] = __builtin_amdgcn_mfma_f32_16x16x32_f16(a0, bf1, acc[0][1], 0, 0, 0);
                acc[1][1] = __builtin_amdgcn_mfma_f32_16x16x32_f16(a1, bf1, acc[1][1], 0, 0, 0);
            }
            // ---- odd half h=2ks+1 (gates 2,3) ----
            {
                const int h = 2 * ks + 1;
                WAIT_LGKM0;
                if (h + 2 < NH0) {
                    const int hs = h + 2, kss = hs >> 1, gb = (hs & 1) * 2;
                    f16* db = wbuf + ((hs % 3) << 10);
                    #pragma unroll
                    for (int d = 0; d < 2; d++)
                        GLOAD_LDS(W0 + ((size_t)(kss * 64 + (gb + d) * 16 + w)) * 512 + l * 8, db + d * 512);
                    wait_vm<4>();
                } else if (h + 1 < NH0) {
                    wait_vm<2>();
                } else {
                    wait_vm<0>();
                }
                const f16* rb = wbuf + ((h % 3) << 10);
                f16x8 bf0 = *(const f16x8*)(rb + l * 8);
                f16x8 bf1 = *(const f16x8*)(rb + 512 + l * 8);
                acc[0][2] = __builtin_amdgcn_mfma_f32_16x16x32_f16(a0, bf0, acc[0][2], 0, 0, 0);
                acc[1][2] = __builtin_amdgcn_mfma_f32_16x16x32_f16(a1, bf0, acc[1][2], 0, 0, 0);
                acc[0][3] = __builtin_amdgcn_mfma_f32_16x16x32_f16(a0, bf1, acc[0][3], 0, 0, 0);
                acc[1][3] = __builtin_amdgcn_mfma_f32_16x16x32_f16(a1, bf1, acc[1][3], 0, 0, 0);
            }
        }
        // cross-section prefetch: gates1 halves 0,1
        WAIT_LGKM0;
        #pragma unroll
        for (int d = 0; d < 2; d++)
            GLOAD_LDS(W1 + ((size_t)(d * 16 + w)) * 512 + l * 8, wbuf + d * 512);
        #pragma unroll
        for (int d = 0; d < 2; d++)
            GLOAD_LDS(W1 + ((size_t)((2 + d) * 16 + w)) * 512 + l * 8, wbuf + 1024 + d * 512);

        // epilogue: c0,h0
        f16 hnew[2][4];
        #pragma unroll
        for (int mt = 0; mt < 2; mt++)
            #pragma unroll
            for (int r = 0; r < 4; r++) {
                float ig = sigmoidf_(acc[mt][0][r]);
                float fg = sigmoidf_(acc[mt][1][r]);
                float gv = tanhf_   (acc[mt][2][r]);
                float og = sigmoidf_(acc[mt][3][r]);
                float c  = fmaf(fg, c0s[mt][r], ig * gv);
                c0s[mt][r] = c;
                hnew[mt][r] = (f16)(og * tanhf_(c));
            }
        __syncthreads();   // B2: all gates0 A-reads done
        #pragma unroll
        for (int mt = 0; mt < 2; mt++)
            #pragma unroll
            for (int r = 0; r < 4; r++)
                A[mt * 16 + m0 + r][H0COL + u] = hnew[mt][r];
        __syncthreads();   // B3: h0 visible

        // ======== gates1: C[32x1024] = A[:,160:672] * W1 (16 slices, 32 halves) ========
        #pragma unroll
        for (int mt = 0; mt < 2; mt++)
            #pragma unroll
            for (int g = 0; g < 4; g++) {
                float b = b1v[g];
                acc[mt][g] = (f32x4){b, b, b, b};
            }
        #pragma unroll 1
        for (int ks = 0; ks < NS1; ks++) {
            {
                const int h = 2 * ks;
                WAIT_LGKM0;
                if (h + 2 < NH1) {
                    const int hs = h + 2, kss = hs >> 1, gb = (hs & 1) * 2;
                    f16* db = wbuf + ((hs % 3) << 10);
                    #pragma unroll
                    for (int d = 0; d < 2; d++)
                        GLOAD_LDS(W1 + ((size_t)(kss * 64 + (gb + d) * 16 + w)) * 512 + l * 8, db + d * 512);
                    wait_vm<4>();
                } else {
                    wait_vm<2>();
                }
                a0 = *(const f16x8*)&A[lm     ][H0COL + ks * 32 + lk];
                a1 = *(const f16x8*)&A[16 + lm][H0COL + ks * 32 + lk];
                const f16* rb = wbuf + ((h % 3) << 10);
                f16x8 bf0 = *(const f16x8*)(rb + l * 8);
                f16x8 bf1 = *(const f16x8*)(rb + 512 + l * 8);
                acc[0][0] = __builtin_amdgcn_mfma_f32_16x16x32_f16(a0, bf0, acc[0][0], 0, 0, 0);
                acc[1][0] = __builtin_amdgcn_mfma_f32_16x16x32_f16(a1, bf0, acc[1][0], 0, 0, 0);
                acc[0][1] = __builtin_amdgcn_mfma_f32_16x16x32_f16(a0, bf1, acc[0][1], 0, 0, 0);
                acc[1][1] = __builtin_amdgcn_mfma_f32_16x16x32_f16(a1, bf1, acc[1][1], 0, 0, 0);
            }
            {
                const int h = 2 * ks + 1;
                WAIT_LGKM0;
                if (h + 2 < NH1) {
                    const int hs = h + 2, kss = hs >> 1, gb = (hs & 1) * 2;
                    f16* db = wbuf + ((hs % 3) << 10);
                    #pragma unroll
                    for (int d = 0; d < 2; d++)
                        GLOAD_LDS(W1 + ((size_t)(kss * 64 + (gb + d) * 16 + w)) * 512 + l * 8, db + d * 512);
                    wait_vm<4>();
                } else if (h + 1 < NH1) {
                    wait_vm<2>();
                } else {
                    wait_vm<0>();
                }
                const f16* rb = wbuf + ((h % 3) << 10);
                f16x8 bf0 = *(const f16x8*)(rb + l * 8);
                f16x8 bf1 = *(const f16x8*)(rb + 512 + l * 8);
                acc[0][2] = __builtin_amdgcn_mfma_f32_16x16x32_f16(a0, bf0, acc[0][2], 0, 0, 0);
                acc[1][2] = __builtin_amdgcn_mfma_f32_16x16x32_f16(a1, bf0, acc[1][2], 0, 0, 0);
                acc[0][3] = __builtin_amdgcn_mfma_f32_16x16x32_f16(a0, bf1, acc[0][3], 0, 0, 0);
                acc[1][3] = __builtin_amdgcn_mfma_f32_16x16x32_f16(a1, bf1, acc[1][3], 0, 0, 0);
            }
        }
        // cross-section prefetch: adv slices 0,1 (1 frag each)
        WAIT_LGKM0;
        GLOAD_LDS(WA + ((size_t)(0 * 16 + w)) * 512 + l * 8, wbuf);
        GLOAD_LDS(WA + ((size_t)(1 * 16 + w)) * 512 + l * 8, wbuf + 1024);

        // epilogue: c1,h1
        #pragma unroll
        for (int mt = 0; mt < 2; mt++)
            #pragma unroll
            for (int r = 0; r < 4; r++) {
                float ig = sigmoidf_(acc[mt][0][r]);
                float fg = sigmoidf_(acc[mt][1][r]);
                float gv = tanhf_   (acc[mt][2][r]);
                float og = sigmoidf_(acc[mt][3][r]);
                float c  = fmaf(fg, c1s[mt][r], ig * gv);
                c1s[mt][r] = c;
                hnew[mt][r] = (f16)(og * tanhf_(c));
            }
        __syncthreads();   // B4: all gates1 A-reads done
        #pragma unroll
        for (int mt = 0; mt < 2; mt++)
            #pragma unroll
            for (int r = 0; r < 4; r++)
                A[mt * 16 + m0 + r][H1COL + u] = hnew[mt][r];
        __syncthreads();   // B5: h1 visible

        // ======== adv: C[32x256] = A[:,416:672] * WA (8 slices, 1 frag/wave) ========
        f32x4 accA[2];
        #pragma unroll
        for (int mt = 0; mt < 2; mt++) {
            float b = bAv;
            accA[mt] = (f32x4){b, b, b, b};
        }
        #pragma unroll 1
        for (int ks = 0; ks < NSA; ks++) {
            WAIT_LGKM0;
            if (ks + 2 < NSA) {
                GLOAD_LDS(WA + ((size_t)((ks + 2) * 16 + w)) * 512 + l * 8,
                          wbuf + (((ks + 2) % 3) << 10));
                wait_vm<2>();
            } else if (ks + 1 < NSA) {
                wait_vm<1>();
            } else {
                wait_vm<0>();
            }
            f16x8 aa0 = *(const f16x8*)&A[lm     ][H1COL + ks * 32 + lk];
            f16x8 aa1 = *(const f16x8*)&A[16 + lm][H1COL + ks * 32 + lk];
            const f16* rb = wbuf + ((ks % 3) << 10);
            f16x8 bf = *(const f16x8*)(rb + l * 8);
            accA[0] = __builtin_amdgcn_mfma_f32_16x16x32_f16(aa0, bf, accA[0], 0, 0, 0);
            accA[1] = __builtin_amdgcn_mfma_f32_16x16x32_f16(aa1, bf, accA[1], 0, 0, 0);
        }
        float s[2][4];
        #pragma unroll
        for (int mt = 0; mt < 2; mt++)
            #pragma unroll
            for (int r = 0; r < 4; r++)
                s[mt][r] = fmaxf(accA[mt][r], 0.f) * wa2v;
        #pragma unroll
        for (int msk = 1; msk < 16; msk <<= 1)
            #pragma unroll
            for (int mt = 0; mt < 2; mt++)
                #pragma unroll
                for (int r = 0; r < 4; r++)
                    s[mt][r] += __shfl_xor(s[mt][r], msk, 64);
        if (lm == 0) {
            #pragma unroll
            for (int mt = 0; mt < 2; mt++)
                #pragma unroll
                for (int r = 0; r < 4; r++)
                    red[w][mt * 16 + m0 + r] = s[mt][r];
        }
        __syncthreads();   // B6: red ready
        if (tid < MROWS) {
            float o = ba2v;
            #pragma unroll
            for (int w2 = 0; w2 < 16; w2++) o += red[w2][tid];
            out[(size_t)t * BTOT + row0 + tid] = o;
        }
    }
}

extern "C" void kernel_launch(void* const* d_in, const int* in_sizes, int n_in,
                              void* d_out, int out_size, void* d_ws, size_t ws_size,
                              hipStream_t stream)
{
    const float* x    = (const float*)d_in[0];
    const float* Wih0 = (const float*)d_in[1];
    const float* Whh0 = (const float*)d_in[2];
    const float* bih0 = (const float*)d_in[3];
    const float* bhh0 = (const float*)d_in[4];
    const float* Wih1 = (const float*)d_in[5];
    const float* Whh1 = (const float*)d_in[6];
    const float* bih1 = (const float*)d_in[7];
    const float* bhh1 = (const float*)d_in[8];
    const float* Wa1  = (const float*)d_in[9];
    const float* ba1  = (const float*)d_in[10];
    const float* Wa2  = (const float*)d_in[11];
    const float* ba2  = (const float*)d_in[12];

    f16*   wsf = (f16*)d_ws;
    float* wsb = (float*)((char*)d_ws + (size_t)F16TOT * sizeof(f16));
    float* out = (float*)d_out;

    hipLaunchKernelGGL(prep, dim3(PREP_TOT / 256), dim3(256), 0, stream,
                       Wih0, Whh0, bih0, bhh0, Wih1, Whh1, bih1, bhh1, Wa1, wsf, wsb);
    hipLaunchKernelGGL(lstm_mfma, dim3(NBLK), dim3(NTHR), 0, stream,
                       x, wsf, wsb, Wa2, ba1, ba2, out);
}

// Round 8
// 2162.326 us; speedup vs baseline: 1.3386x; 1.3386x over previous
//
#include <hip/hip_runtime.h>
#include <cstdint>
#include <cstddef>

#define T_STEPS 100
#define IN_DIM  140
#define HDIM    256
#define BTOT    4096
#define MROWS   16
#define NBLK    (BTOT/MROWS)  // 256 blocks
#define NTHR    512           // 8 waves

typedef _Float16 f16;
typedef _Float16 f16x8 __attribute__((ext_vector_type(8)));
typedef float    f32x4 __attribute__((ext_vector_type(4)));

// K dims (padded to 32): gates0 K=416 (x 160 incl pad + h0 256), gates1 K=512, adv K=256
#define NS0 13
#define NS1 16
#define NSA 8
// fragment = 64 lanes x 8 f16 = 512 elems = 1KB
#define E0 (NS0*64*512)       // 425984
#define E1 (NS1*64*512)       // 524288
#define EA (NSA*16*512)       // 65536
#define F16TOT (E0+E1+EA)     // 1015808 f16 = ~2MB
#define EB 2048               // 2x1024 fp32 biases
#define PREP_TOT (F16TOT+EB)  // 1017856 = 3976*256

// LDS activation tile: cols 0-159 x(padded), 160-415 h0, 416-671 h1, 672-679 pad
#define ACOLS 680
#define H0COL 160
#define H1COL 416

__device__ __forceinline__ float sigmoidf_(float x) {
    return 1.0f / (1.0f + __expf(-x));
}
__device__ __forceinline__ float tanhf_(float x) {
    return 1.0f - 2.0f / (__expf(2.0f * x) + 1.0f);
}

// Pack weights into MFMA B-fragment order (fp16) + folded fp32 biases.
// Frag (ks, nt): lane l, elem e -> B[k = ks*32 + (l>>4)*8 + e][n = nt*16 + (l&15)]
__global__ void prep(const float* __restrict__ Wih0, const float* __restrict__ Whh0,
                     const float* __restrict__ bih0, const float* __restrict__ bhh0,
                     const float* __restrict__ Wih1, const float* __restrict__ Whh1,
                     const float* __restrict__ bih1, const float* __restrict__ bhh1,
                     const float* __restrict__ Wa1,  f16* __restrict__ wsf,
                     float* __restrict__ wsb)
{
    int idx = blockIdx.x * 256 + threadIdx.x;
    if (idx < E0) {
        int e = idx & 7, l = (idx >> 3) & 63, fi = idx >> 9;
        int nt = fi & 63, ks = fi >> 6;
        int k = ks * 32 + ((l >> 4) << 3) + e;
        int n = nt * 16 + (l & 15);
        float v = (k < 160) ? (k < IN_DIM ? Wih0[n * IN_DIM + k] : 0.f)
                            : Whh0[n * HDIM + (k - 160)];
        wsf[idx] = (f16)v;
    } else if (idx < E0 + E1) {
        int i2 = idx - E0;
        int e = i2 & 7, l = (i2 >> 3) & 63, fi = i2 >> 9;
        int nt = fi & 63, ks = fi >> 6;
        int k = ks * 32 + ((l >> 4) << 3) + e;
        int n = nt * 16 + (l & 15);
        float v = (k < HDIM) ? Wih1[n * HDIM + k] : Whh1[n * HDIM + (k - HDIM)];
        wsf[idx] = (f16)v;
    } else if (idx < F16TOT) {
        int i3 = idx - (E0 + E1);
        int e = i3 & 7, l = (i3 >> 3) & 63, fi = i3 >> 9;
        int nt = fi & 15, ks = fi >> 4;
        int k = ks * 32 + ((l >> 4) << 3) + e;
        int j = nt * 16 + (l & 15);
        wsf[idx] = (f16)Wa1[j * HDIM + k];
    } else if (idx < PREP_TOT) {
        int i4 = idx - F16TOT;
        if (i4 < 1024) wsb[i4] = bih0[i4] + bhh0[i4];
        else           wsb[i4] = bih1[i4 - 1024] + bhh1[i4 - 1024];
    }
}

#define GLOAD_LDS(gsrc, ldst)                                              \
    __builtin_amdgcn_global_load_lds(                                      \
        (const __attribute__((address_space(1))) void*)(gsrc),             \
        (__attribute__((address_space(3))) void*)(ldst), 16, 0, 0)

// Stage this wave's 8 fragments (gates sections, NT=64) of one k-slice.
__device__ __forceinline__ void stage8(const f16* slice, f16* dst, int w, int l) {
    #pragma unroll
    for (int g = 0; g < 4; g++)
        #pragma unroll
        for (int q = 0; q < 2; q++) {
            const f16* src = slice + (size_t)(g * 16 + 2 * w + q) * 512 + l * 8;
            GLOAD_LDS(src, dst + (g * 2 + q) * 512);
        }
}

template<int N>
__device__ __forceinline__ void wait_vm() {
    asm volatile("s_waitcnt vmcnt(%0)" :: "i"(N) : "memory");
    __builtin_amdgcn_sched_barrier(0);
}
#define WAIT_LGKM0 do { asm volatile("s_waitcnt lgkmcnt(0)" ::: "memory"); \
                        __builtin_amdgcn_sched_barrier(0); } while (0)
// lgkm-only barrier: does NOT drain vmcnt, so global_load_lds prefetches
// stay in flight across it. Safe: every cross-wave LDS hazard here is a
// ds-op (lgkm-tracked); gload_lds targets are wave-private.
#define BAR_LG do { asm volatile("s_waitcnt lgkmcnt(0)" ::: "memory");     \
                    __builtin_amdgcn_sched_barrier(0);                     \
                    __builtin_amdgcn_s_barrier();                          \
                    __builtin_amdgcn_sched_barrier(0); } while (0)

__global__ __launch_bounds__(NTHR) void lstm_mfma(
    const float* __restrict__ x, const f16* __restrict__ wsf,
    const float* __restrict__ wsb, const float* __restrict__ Wa2,
    const float* __restrict__ ba1, const float* __restrict__ ba2,
    float* __restrict__ out)
{
    __shared__ __align__(16) f16 A[MROWS][ACOLS];       // 21760 B
    __shared__ __align__(16) f16 Bst[8][2][4096];       // 8 waves x 2 bufs x 8KB = 128KB
    __shared__ float red[8][MROWS];                     // 512 B

    const int tid = threadIdx.x;
    const int l   = tid & 63;
    const int w   = tid >> 6;         // wave 0..7
    const int lm  = l & 15;           // A-row / C-col(n) lane coord
    const int lk  = (l >> 4) << 3;    // k-offset within a 32-slice
    const int m0  = (l >> 4) << 2;    // C rows m0..m0+3
    const int row0 = blockIdx.x * MROWS;

    const f16* W0 = wsf;
    const f16* W1 = wsf + E0;
    const f16* WA = wsf + E0 + E1;
    f16* wbuf = &Bst[w][0][0];        // two 4096-f16 buffers

    // zero activation tile
    for (int i = tid; i < MROWS * ACOLS; i += NTHR) ((f16*)A)[i] = (f16)0.f;

    const int u0 = (2 * w) * 16 + lm;
    const int u1 = (2 * w + 1) * 16 + lm;
    float b0v[2][4], b1v[2][4];
    #pragma unroll
    for (int g = 0; g < 4; g++) {
        b0v[0][g] = wsb[g * 256 + u0];          b0v[1][g] = wsb[g * 256 + u1];
        b1v[0][g] = wsb[1024 + g * 256 + u0];   b1v[1][g] = wsb[1024 + g * 256 + u1];
    }
    const float bAv[2]  = { ba1[u0], ba1[u1] };
    const float wa2v[2] = { Wa2[u0], Wa2[u1] };
    const float ba2v    = ba2[0];

    // adv weights persistent in VGPRs: 16 frags x 4 VGPR = 64 VGPR
    f16x8 advw[16];
    #pragma unroll
    for (int ks = 0; ks < NSA; ks++) {
        advw[2 * ks + 0] = *(const f16x8*)(WA + (size_t)(ks * 16 + 2 * w + 0) * 512 + l * 8);
        advw[2 * ks + 1] = *(const f16x8*)(WA + (size_t)(ks * 16 + 2 * w + 1) * 512 + l * 8);
    }

    float c0s[2][4], c1s[2][4];
    #pragma unroll
    for (int q = 0; q < 2; q++)
        #pragma unroll
        for (int r = 0; r < 4; r++) { c0s[q][r] = 0.f; c1s[q][r] = 0.f; }

    __syncthreads();   // A zeroed

    // prologue: stage x_0 + gates0 slice 0 (-> buf0, p=0)
    for (int i = tid; i < MROWS * IN_DIM; i += NTHR) {
        int b = i / IN_DIM, k = i - b * IN_DIM;
        A[b][k] = (f16)x[(size_t)(row0 + b) * (T_STEPS * IN_DIM) + k];
    }
    stage8(W0, wbuf, w, l);
    __syncthreads();   // full drain (prologue only): x0 + s0 resident

    #pragma unroll 1
    for (int t = 0; t < T_STEPS; t++) {
        const int p = t & 1;   // buffer parity (29 stages/step -> flips per step)

        // ======== gates0: 13 slices; s_ks in buf[(ks+p)&1] ========
        f32x4 acc[2][4];
        #pragma unroll
        for (int q = 0; q < 2; q++)
            #pragma unroll
            for (int g = 0; g < 4; g++) {
                float b = b0v[q][g];
                acc[q][g] = (f32x4){b, b, b, b};
            }
        #pragma unroll 1
        for (int ks = 0; ks < NS0; ks++) {
            WAIT_LGKM0;    // prior reads of the buffer we're about to overwrite are done
            {
                f16* db = wbuf + (((ks + 1 + p) & 1) << 12);
                if (ks < NS0 - 1) stage8(W0 + (size_t)(ks + 1) * 64 * 512, db, w, l);
                else              stage8(W1, db, w, l);   // gates1 slice 0
            }
            wait_vm<8>();  // slice ks resident (8 newer in flight)
            const f16* rb = wbuf + (((ks + p) & 1) << 12);
            f16x8 a0 = *(const f16x8*)&A[lm][ks * 32 + lk];
            #pragma unroll
            for (int g = 0; g < 4; g++)
                #pragma unroll
                for (int q = 0; q < 2; q++) {
                    f16x8 bf = *(const f16x8*)(rb + (g * 2 + q) * 512 + l * 8);
                    acc[q][g] = __builtin_amdgcn_mfma_f32_16x16x32_f16(a0, bf, acc[q][g], 0, 0, 0);
                }
        }

        // epilogue: c0,h0
        f16 hnew[2][4];
        #pragma unroll
        for (int q = 0; q < 2; q++)
            #pragma unroll
            for (int r = 0; r < 4; r++) {
                float ig = sigmoidf_(acc[q][0][r]);
                float fg = sigmoidf_(acc[q][1][r]);
                float gv = tanhf_   (acc[q][2][r]);
                float og = sigmoidf_(acc[q][3][r]);
                float c  = fmaf(fg, c0s[q][r], ig * gv);
                c0s[q][r] = c;
                hnew[q][r] = (f16)(og * tanhf_(c));
            }
        BAR_LG;            // B2: all gates0 A-reads done (lgkm-only; prefetch stays in flight)
        #pragma unroll
        for (int r = 0; r < 4; r++) {
            A[m0 + r][H0COL + u0] = hnew[0][r];
            A[m0 + r][H0COL + u1] = hnew[1][r];
        }
        BAR_LG;            // B3: h0 visible

        // ======== gates1: 16 slices; s_ks in buf[(ks+1+p)&1] ========
        #pragma unroll
        for (int q = 0; q < 2; q++)
            #pragma unroll
            for (int g = 0; g < 4; g++) {
                float b = b1v[q][g];
                acc[q][g] = (f32x4){b, b, b, b};
            }
        #pragma unroll 1
        for (int ks = 0; ks < NS1; ks++) {
            WAIT_LGKM0;
            {
                f16* db = wbuf + (((ks + p) & 1) << 12);
                if (ks < NS1 - 1) stage8(W1 + (size_t)(ks + 1) * 64 * 512, db, w, l);
                else              stage8(W0, db, w, l);   // next step's gates0 slice 0
            }
            wait_vm<8>();
            const f16* rb = wbuf + (((ks + 1 + p) & 1) << 12);
            f16x8 a0 = *(const f16x8*)&A[lm][H0COL + ks * 32 + lk];
            #pragma unroll
            for (int g = 0; g < 4; g++)
                #pragma unroll
                for (int q = 0; q < 2; q++) {
                    f16x8 bf = *(const f16x8*)(rb + (g * 2 + q) * 512 + l * 8);
                    acc[q][g] = __builtin_amdgcn_mfma_f32_16x16x32_f16(a0, bf, acc[q][g], 0, 0, 0);
                }
        }

        // epilogue: c1,h1
        #pragma unroll
        for (int q = 0; q < 2; q++)
            #pragma unroll
            for (int r = 0; r < 4; r++) {
                float ig = sigmoidf_(acc[q][0][r]);
                float fg = sigmoidf_(acc[q][1][r]);
                float gv = tanhf_   (acc[q][2][r]);
                float og = sigmoidf_(acc[q][3][r]);
                float c  = fmaf(fg, c1s[q][r], ig * gv);
                c1s[q][r] = c;
                hnew[q][r] = (f16)(og * tanhf_(c));
            }
        BAR_LG;            // B4: all gates1 A-reads done
        #pragma unroll
        for (int r = 0; r < 4; r++) {
            A[m0 + r][H1COL + u0] = hnew[0][r];
            A[m0 + r][H1COL + u1] = hnew[1][r];
        }
        BAR_LG;            // B5: h1 visible

        // ======== adv: register-resident weights, no VMEM ========
        f32x4 accA[2];
        #pragma unroll
        for (int q = 0; q < 2; q++) {
            float b = bAv[q];
            accA[q] = (f32x4){b, b, b, b};
        }
        #pragma unroll
        for (int ks = 0; ks < NSA; ks++) {
            f16x8 a0 = *(const f16x8*)&A[lm][H1COL + ks * 32 + lk];
            accA[0] = __builtin_amdgcn_mfma_f32_16x16x32_f16(a0, advw[2 * ks + 0], accA[0], 0, 0, 0);
            accA[1] = __builtin_amdgcn_mfma_f32_16x16x32_f16(a0, advw[2 * ks + 1], accA[1], 0, 0, 0);
        }

        // ---- overlap: stage x_{t+1} into A's x region (dead after gates0) ----
        {
            const int tn = (t + 1 < T_STEPS) ? (t + 1) : t;
            for (int i = tid; i < MROWS * IN_DIM; i += NTHR) {
                int b = i / IN_DIM, k = i - b * IN_DIM;
                A[b][k] = (f16)x[(size_t)(row0 + b) * (T_STEPS * IN_DIM) + (size_t)tn * IN_DIM + k];
            }
        }

        // ---- reduce + output ----
        float s[4];
        #pragma unroll
        for (int r = 0; r < 4; r++)
            s[r] = fmaxf(accA[0][r], 0.f) * wa2v[0] + fmaxf(accA[1][r], 0.f) * wa2v[1];
        #pragma unroll
        for (int msk = 1; msk < 16; msk <<= 1)
            #pragma unroll
            for (int r = 0; r < 4; r++)
                s[r] += __shfl_xor(s[r], msk, 64);
        if (lm == 0) {
            #pragma unroll
            for (int r = 0; r < 4; r++) red[w][m0 + r] = s[r];
        }
        BAR_LG;            // B6: red + x_{t+1} visible
        if (tid < MROWS) {
            float o = ba2v;
            #pragma unroll
            for (int w2 = 0; w2 < 8; w2++) o += red[w2][tid];
            out[(size_t)t * BTOT + row0 + tid] = o;
        }
    }
}

extern "C" void kernel_launch(void* const* d_in, const int* in_sizes, int n_in,
                              void* d_out, int out_size, void* d_ws, size_t ws_size,
                              hipStream_t stream)
{
    const float* x    = (const float*)d_in[0];
    const float* Wih0 = (const float*)d_in[1];
    const float* Whh0 = (const float*)d_in[2];
    const float* bih0 = (const float*)d_in[3];
    const float* bhh0 = (const float*)d_in[4];
    const float* Wih1 = (const float*)d_in[5];
    const float* Whh1 = (const float*)d_in[6];
    const float* bih1 = (const float*)d_in[7];
    const float* bhh1 = (const float*)d_in[8];
    const float* Wa1  = (const float*)d_in[9];
    const float* ba1  = (const float*)d_in[10];
    const float* Wa2  = (const float*)d_in[11];
    const float* ba2  = (const float*)d_in[12];

    f16*   wsf = (f16*)d_ws;
    float* wsb = (float*)((char*)d_ws + (size_t)F16TOT * sizeof(f16));
    float* out = (float*)d_out;

    hipLaunchKernelGGL(prep, dim3(PREP_TOT / 256), dim3(256), 0, stream,
                       Wih0, Whh0, bih0, bhh0, Wih1, Whh1, bih1, bhh1, Wa1, wsf, wsb);
    hipLaunchKernelGGL(lstm_mfma, dim3(NBLK), dim3(NTHR), 0, stream,
                       x, wsf, wsb, Wa2, ba1, ba2, out);
}

// Round 9
// 1998.178 us; speedup vs baseline: 1.4485x; 1.0821x over previous
//
#include <hip/hip_runtime.h>
#include <cstdint>
#include <cstddef>

#define T_STEPS 100
#define IN_DIM  140
#define HDIM    256
#define BTOT    4096
#define MROWS   16
#define NBLK    (BTOT/MROWS)  // 256 blocks
#define NTHR    512           // 8 waves

typedef _Float16 f16;
typedef _Float16 f16x8 __attribute__((ext_vector_type(8)));
typedef float    f32x4 __attribute__((ext_vector_type(4)));

// K dims (padded to 32): gates0 K=416 (x 160 incl pad + h0 256), gates1 K=512, adv K=256
#define NS0 13
#define NS1 16
#define NSA 8
// fragment = 64 lanes x 8 f16 = 512 elems = 1KB
#define E0 (NS0*64*512)       // 425984
#define E1 (NS1*64*512)       // 524288
#define EA (NSA*16*512)       // 65536
#define F16TOT (E0+E1+EA)     // 1015808 f16 = ~2MB
#define EB 2048               // 2x1024 fp32 biases
#define PREP_TOT (F16TOT+EB)  // 1017856 = 3976*256

// LDS activation tile: cols 0-159 x(padded), 160-415 h0, 416-671 h1, 672-679 pad
#define ACOLS 680
#define H0COL 160
#define H1COL 416

__device__ __forceinline__ float sigmoidf_(float x) {
    return 1.0f / (1.0f + __expf(-x));
}
__device__ __forceinline__ float tanhf_(float x) {
    return 1.0f - 2.0f / (__expf(2.0f * x) + 1.0f);
}

// Pack weights into MFMA B-fragment order (fp16) + folded fp32 biases.
// Frag (ks, nt): lane l, elem e -> B[k = ks*32 + (l>>4)*8 + e][n = nt*16 + (l&15)]
__global__ void prep(const float* __restrict__ Wih0, const float* __restrict__ Whh0,
                     const float* __restrict__ bih0, const float* __restrict__ bhh0,
                     const float* __restrict__ Wih1, const float* __restrict__ Whh1,
                     const float* __restrict__ bih1, const float* __restrict__ bhh1,
                     const float* __restrict__ Wa1,  f16* __restrict__ wsf,
                     float* __restrict__ wsb)
{
    int idx = blockIdx.x * 256 + threadIdx.x;
    if (idx < E0) {
        int e = idx & 7, l = (idx >> 3) & 63, fi = idx >> 9;
        int nt = fi & 63, ks = fi >> 6;
        int k = ks * 32 + ((l >> 4) << 3) + e;
        int n = nt * 16 + (l & 15);
        float v = (k < 160) ? (k < IN_DIM ? Wih0[n * IN_DIM + k] : 0.f)
                            : Whh0[n * HDIM + (k - 160)];
        wsf[idx] = (f16)v;
    } else if (idx < E0 + E1) {
        int i2 = idx - E0;
        int e = i2 & 7, l = (i2 >> 3) & 63, fi = i2 >> 9;
        int nt = fi & 63, ks = fi >> 6;
        int k = ks * 32 + ((l >> 4) << 3) + e;
        int n = nt * 16 + (l & 15);
        float v = (k < HDIM) ? Wih1[n * HDIM + k] : Whh1[n * HDIM + (k - HDIM)];
        wsf[idx] = (f16)v;
    } else if (idx < F16TOT) {
        int i3 = idx - (E0 + E1);
        int e = i3 & 7, l = (i3 >> 3) & 63, fi = i3 >> 9;
        int nt = fi & 15, ks = fi >> 4;
        int k = ks * 32 + ((l >> 4) << 3) + e;
        int j = nt * 16 + (l & 15);
        wsf[idx] = (f16)Wa1[j * HDIM + k];
    } else if (idx < PREP_TOT) {
        int i4 = idx - F16TOT;
        if (i4 < 1024) wsb[i4] = bih0[i4] + bhh0[i4];
        else           wsb[i4] = bih1[i4 - 1024] + bhh1[i4 - 1024];
    }
}

#define GLOAD_LDS(gsrc, ldst)                                              \
    __builtin_amdgcn_global_load_lds(                                      \
        (const __attribute__((address_space(1))) void*)(gsrc),             \
        (__attribute__((address_space(3))) void*)(ldst), 16, 0, 0)

// lgkm-only barrier: does NOT drain vmcnt, so in-flight global loads
// (B-frag register prefetch) cross it. Safe: every cross-wave LDS hazard
// is a ds-op (lgkm-tracked).
#define BAR_LG do { asm volatile("s_waitcnt lgkmcnt(0)" ::: "memory");     \
                    __builtin_amdgcn_sched_barrier(0);                     \
                    __builtin_amdgcn_s_barrier();                          \
                    __builtin_amdgcn_sched_barrier(0); } while (0)

// B-fragment load: f = g*2+q -> frag column nt = (f>>1)*16 + 2w + (f&1)
__device__ __forceinline__ f16x8 ldfrag(const f16* base, int f, int w, int l) {
    return *(const f16x8*)(base + ((size_t)(((f >> 1) << 4) + 2 * w + (f & 1)) << 9) + l * 8);
}

__global__ __launch_bounds__(NTHR) void lstm_mfma(
    const float* __restrict__ x, const f16* __restrict__ wsf,
    const float* __restrict__ wsb, const float* __restrict__ Wa2,
    const float* __restrict__ ba1, const float* __restrict__ ba2,
    float* __restrict__ out)
{
    __shared__ __align__(16) f16 A[MROWS][ACOLS];       // 21760 B
    __shared__ __align__(16) f16 advL[8 * 16 * 512];    // 128 KB: adv weights, LDS-pinned
    __shared__ float red[8][MROWS];                     // 512 B

    const int tid = threadIdx.x;
    const int l   = tid & 63;
    const int w   = tid >> 6;         // wave 0..7
    const int lm  = l & 15;           // A-row / C-col(n) lane coord
    const int lk  = (l >> 4) << 3;    // k-offset within a 32-slice
    const int m0  = (l >> 4) << 2;    // C rows m0..m0+3
    const int row0 = blockIdx.x * MROWS;

    const f16* W0 = wsf;
    const f16* W1 = wsf + E0;
    const f16* WA = wsf + E0 + E1;

    // zero activation tile
    for (int i = tid; i < MROWS * ACOLS; i += NTHR) ((f16*)A)[i] = (f16)0.f;

    const int u0 = (2 * w) * 16 + lm;
    const int u1 = (2 * w + 1) * 16 + lm;
    float b0v[2][4], b1v[2][4];
    #pragma unroll
    for (int g = 0; g < 4; g++) {
        b0v[0][g] = wsb[g * 256 + u0];          b0v[1][g] = wsb[g * 256 + u1];
        b1v[0][g] = wsb[1024 + g * 256 + u0];   b1v[1][g] = wsb[1024 + g * 256 + u1];
    }
    const float bAv[2]  = { ba1[u0], ba1[u1] };
    const float wa2v[2] = { Wa2[u0], Wa2[u1] };
    const float ba2v    = ba2[0];

    // stage adv weights into LDS once (wave w's 16 frags at advL[w*16 + fi])
    #pragma unroll
    for (int fi = 0; fi < 16; fi++) {
        const f16* src = WA + ((size_t)(((fi >> 1) << 4) + 2 * w + (fi & 1)) << 9) + l * 8;
        GLOAD_LDS(src, advL + (size_t)(w * 16 + fi) * 512);
    }

    float c0s[2][4], c1s[2][4];
    #pragma unroll
    for (int q = 0; q < 2; q++)
        #pragma unroll
        for (int r = 0; r < 4; r++) { c0s[q][r] = 0.f; c1s[q][r] = 0.f; }

    // prologue: stage x_0; preload gates0 slice 0 into cur
    for (int i = tid; i < MROWS * IN_DIM; i += NTHR) {
        int b = i / IN_DIM, k = i - b * IN_DIM;
        A[b][k] = (f16)x[(size_t)(row0 + b) * (T_STEPS * IN_DIM) + k];
    }
    f16x8 cur[8];
    #pragma unroll
    for (int f = 0; f < 8; f++) cur[f] = ldfrag(W0, f, w, l);

    __syncthreads();   // full drain (prologue only): A zeroed + x0 + advL resident

    #pragma unroll 1
    for (int t = 0; t < T_STEPS; t++) {
        // ======== gates0: 13 slices, B in registers (depth-1 prefetch) ========
        f32x4 acc[2][4];
        #pragma unroll
        for (int q = 0; q < 2; q++)
            #pragma unroll
            for (int g = 0; g < 4; g++) {
                float b = b0v[q][g];
                acc[q][g] = (f32x4){b, b, b, b};
            }
        #pragma unroll 1
        for (int ks = 0; ks < NS0; ks++) {
            const f16* nb = (ks < NS0 - 1) ? (W0 + (size_t)(ks + 1) * (64 * 512)) : W1;
            f16x8 nxt[8];
            #pragma unroll
            for (int f = 0; f < 8; f++) nxt[f] = ldfrag(nb, f, w, l);
            f16x8 a0 = *(const f16x8*)&A[lm][ks * 32 + lk];
            #pragma unroll
            for (int g = 0; g < 4; g++)
                #pragma unroll
                for (int q = 0; q < 2; q++)
                    acc[q][g] = __builtin_amdgcn_mfma_f32_16x16x32_f16(a0, cur[g * 2 + q], acc[q][g], 0, 0, 0);
            #pragma unroll
            for (int f = 0; f < 8; f++) cur[f] = nxt[f];
        }

        // epilogue: c0,h0
        f16 hnew[2][4];
        #pragma unroll
        for (int q = 0; q < 2; q++)
            #pragma unroll
            for (int r = 0; r < 4; r++) {
                float ig = sigmoidf_(acc[q][0][r]);
                float fg = sigmoidf_(acc[q][1][r]);
                float gv = tanhf_   (acc[q][2][r]);
                float og = sigmoidf_(acc[q][3][r]);
                float c  = fmaf(fg, c0s[q][r], ig * gv);
                c0s[q][r] = c;
                hnew[q][r] = (f16)(og * tanhf_(c));
            }
        BAR_LG;            // B2: all gates0 A-reads done
        #pragma unroll
        for (int r = 0; r < 4; r++) {
            A[m0 + r][H0COL + u0] = hnew[0][r];
            A[m0 + r][H0COL + u1] = hnew[1][r];
        }
        BAR_LG;            // B3: h0 visible

        // ======== gates1: 16 slices (cur carries W1 slice 0 across barriers) ========
        #pragma unroll
        for (int q = 0; q < 2; q++)
            #pragma unroll
            for (int g = 0; g < 4; g++) {
                float b = b1v[q][g];
                acc[q][g] = (f32x4){b, b, b, b};
            }
        #pragma unroll 1
        for (int ks = 0; ks < NS1; ks++) {
            const f16* nb = (ks < NS1 - 1) ? (W1 + (size_t)(ks + 1) * (64 * 512)) : W0;
            f16x8 nxt[8];
            #pragma unroll
            for (int f = 0; f < 8; f++) nxt[f] = ldfrag(nb, f, w, l);
            f16x8 a0 = *(const f16x8*)&A[lm][H0COL + ks * 32 + lk];
            #pragma unroll
            for (int g = 0; g < 4; g++)
                #pragma unroll
                for (int q = 0; q < 2; q++)
                    acc[q][g] = __builtin_amdgcn_mfma_f32_16x16x32_f16(a0, cur[g * 2 + q], acc[q][g], 0, 0, 0);
            #pragma unroll
            for (int f = 0; f < 8; f++) cur[f] = nxt[f];
        }
        // cur now holds next step's gates0 slice 0

        // epilogue: c1,h1
        #pragma unroll
        for (int q = 0; q < 2; q++)
            #pragma unroll
            for (int r = 0; r < 4; r++) {
                float ig = sigmoidf_(acc[q][0][r]);
                float fg = sigmoidf_(acc[q][1][r]);
                float gv = tanhf_   (acc[q][2][r]);
                float og = sigmoidf_(acc[q][3][r]);
                float c  = fmaf(fg, c1s[q][r], ig * gv);
                c1s[q][r] = c;
                hnew[q][r] = (f16)(og * tanhf_(c));
            }
        BAR_LG;            // B4: all gates1 A-reads done
        #pragma unroll
        for (int r = 0; r < 4; r++) {
            A[m0 + r][H1COL + u0] = hnew[0][r];
            A[m0 + r][H1COL + u1] = hnew[1][r];
        }
        BAR_LG;            // B5: h1 visible

        // ======== adv: weights from LDS (pinned), no VMEM ========
        f32x4 accA[2];
        #pragma unroll
        for (int q = 0; q < 2; q++) {
            float b = bAv[q];
            accA[q] = (f32x4){b, b, b, b};
        }
        #pragma unroll
        for (int ks = 0; ks < NSA; ks++) {
            f16x8 a0 = *(const f16x8*)&A[lm][H1COL + ks * 32 + lk];
            f16x8 bf0 = *(const f16x8*)(advL + (size_t)(w * 16 + 2 * ks + 0) * 512 + l * 8);
            f16x8 bf1 = *(const f16x8*)(advL + (size_t)(w * 16 + 2 * ks + 1) * 512 + l * 8);
            accA[0] = __builtin_amdgcn_mfma_f32_16x16x32_f16(a0, bf0, accA[0], 0, 0, 0);
            accA[1] = __builtin_amdgcn_mfma_f32_16x16x32_f16(a0, bf1, accA[1], 0, 0, 0);
        }

        // ---- overlap: stage x_{t+1} into A's x region (dead after gates0) ----
        {
            const int tn = (t + 1 < T_STEPS) ? (t + 1) : t;
            for (int i = tid; i < MROWS * IN_DIM; i += NTHR) {
                int b = i / IN_DIM, k = i - b * IN_DIM;
                A[b][k] = (f16)x[(size_t)(row0 + b) * (T_STEPS * IN_DIM) + (size_t)tn * IN_DIM + k];
            }
        }

        // ---- reduce + output ----
        float s[4];
        #pragma unroll
        for (int r = 0; r < 4; r++)
            s[r] = fmaxf(accA[0][r], 0.f) * wa2v[0] + fmaxf(accA[1][r], 0.f) * wa2v[1];
        #pragma unroll
        for (int msk = 1; msk < 16; msk <<= 1)
            #pragma unroll
            for (int r = 0; r < 4; r++)
                s[r] += __shfl_xor(s[r], msk, 64);
        if (lm == 0) {
            #pragma unroll
            for (int r = 0; r < 4; r++) red[w][m0 + r] = s[r];
        }
        BAR_LG;            // B6: red + x_{t+1} visible
        if (tid < MROWS) {
            float o = ba2v;
            #pragma unroll
            for (int w2 = 0; w2 < 8; w2++) o += red[w2][tid];
            out[(size_t)t * BTOT + row0 + tid] = o;
        }
    }
}

extern "C" void kernel_launch(void* const* d_in, const int* in_sizes, int n_in,
                              void* d_out, int out_size, void* d_ws, size_t ws_size,
                              hipStream_t stream)
{
    const float* x    = (const float*)d_in[0];
    const float* Wih0 = (const float*)d_in[1];
    const float* Whh0 = (const float*)d_in[2];
    const float* bih0 = (const float*)d_in[3];
    const float* bhh0 = (const float*)d_in[4];
    const float* Wih1 = (const float*)d_in[5];
    const float* Whh1 = (const float*)d_in[6];
    const float* bih1 = (const float*)d_in[7];
    const float* bhh1 = (const float*)d_in[8];
    const float* Wa1  = (const float*)d_in[9];
    const float* ba1  = (const float*)d_in[10];
    const float* Wa2  = (const float*)d_in[11];
    const float* ba2  = (const float*)d_in[12];

    f16*   wsf = (f16*)d_ws;
    float* wsb = (float*)((char*)d_ws + (size_t)F16TOT * sizeof(f16));
    float* out = (float*)d_out;

    hipLaunchKernelGGL(prep, dim3(PREP_TOT / 256), dim3(256), 0, stream,
                       Wih0, Whh0, bih0, bhh0, Wih1, Whh1, bih1, bhh1, Wa1, wsf, wsb);
    hipLaunchKernelGGL(lstm_mfma, dim3(NBLK), dim3(NTHR), 0, stream,
                       x, wsf, wsb, Wa2, ba1, ba2, out);
}